// Round 2
// 268.283 us; speedup vs baseline: 1.0746x; 1.0746x over previous
//
#include <hip/hip_runtime.h>
#include <hip/hip_fp16.h>

#define NN 50000
#define EE 800000
#define ET 850000          // EE + NN self-loops
#define NEG 0.2f
#define SCAN_B 1024
#define NBLK ((NN + SCAN_B - 1) / SCAN_B)   // 49
#define GHALF 391          // gemm blocks per mega phase: 391*64 = 25024 rows
#define RHALF 25024
#define HIST_BLKS ((ET + 255) / 256)        // 3321

__device__ __forceinline__ float leaky(float x) { return fmaxf(x, NEG * x); }
__device__ __forceinline__ float elu_f(float x) { return x > 0.f ? x : expm1f(x); }

struct alignas(8) half4 { __half2 a, b; };

typedef _Float16 half8_t __attribute__((ext_vector_type(8)));
typedef float float4_t __attribute__((ext_vector_type(4)));

// ---- MFMA GEMM tile: 16 rows x 128 cols per wave, fused attention logits ----
__device__ __forceinline__
void gemm_tile(const float* __restrict__ Xf, const __half* __restrict__ Xh,
               const __half* __restrict__ Wt, __half* __restrict__ Yh,
               int nrows, int row0, int lane,
               const float* __restrict__ att_s, const float* __restrict__ att_d,
               float* __restrict__ asb, float* __restrict__ adb) {
    int n = lane & 15, quad = lane >> 4;
    float atts_r[8], attd_r[8];
#pragma unroll
    for (int t = 0; t < 8; ++t) {
        atts_r[t] = att_s[t * 16 + n];
        attd_r[t] = att_d[t * 16 + n];
    }
    float4_t acc[8];
#pragma unroll
    for (int t = 0; t < 8; ++t) acc[t] = (float4_t){0.f, 0.f, 0.f, 0.f};
    int rA = row0 + n; if (rA >= nrows) rA = nrows - 1;
#pragma unroll
    for (int ch = 0; ch < 4; ++ch) {
        half8_t a;
        if (Xh) {
            a = *(const half8_t*)(Xh + (size_t)rA * 128 + ch * 32 + quad * 8);
        } else {
            const float* xp = Xf + (size_t)rA * 128 + ch * 32 + quad * 8;
            float4 f0 = *(const float4*)xp;
            float4 f1 = *(const float4*)(xp + 4);
            a = (half8_t){(_Float16)f0.x, (_Float16)f0.y, (_Float16)f0.z, (_Float16)f0.w,
                          (_Float16)f1.x, (_Float16)f1.y, (_Float16)f1.z, (_Float16)f1.w};
        }
#pragma unroll
        for (int t = 0; t < 8; ++t) {
            half8_t b = *(const half8_t*)(Wt + (t * 16 + n) * 128 + ch * 32 + quad * 8);
            acc[t] = __builtin_amdgcn_mfma_f32_16x16x32_f16(a, b, acc[t], 0, 0, 0);
        }
    }
    // C store (fp16): col = t*16 + n, row = quad*4 + rg
#pragma unroll
    for (int rg = 0; rg < 4; ++rg) {
        int row = row0 + quad * 4 + rg;
        if (row < nrows) {
            __half* yp = Yh + (size_t)row * 128 + n;
#pragma unroll
            for (int t = 0; t < 8; ++t)
                yp[t * 16] = __float2half(acc[t][rg]);
        }
    }
    // fused alpha: reduce acc * att over the 16 col-lanes of each quad
#pragma unroll
    for (int rg = 0; rg < 4; ++rg) {
        float ps[4], pd[4];
#pragma unroll
        for (int h = 0; h < 4; ++h) {
            ps[h] = acc[2*h][rg] * atts_r[2*h] + acc[2*h+1][rg] * atts_r[2*h+1];
            pd[h] = acc[2*h][rg] * attd_r[2*h] + acc[2*h+1][rg] * attd_r[2*h+1];
#pragma unroll
            for (int mask = 1; mask < 16; mask <<= 1) {
                ps[h] += __shfl_xor(ps[h], mask, 64);
                pd[h] += __shfl_xor(pd[h], mask, 64);
            }
        }
        int row = row0 + quad * 4 + rg;
        if (n == 0 && row < nrows) {
#pragma unroll
            for (int h = 0; h < 4; ++h) {
                asb[row * 4 + h] = ps[h];
                adb[row * 4 + h] = pd[h];
            }
        }
    }
}

// plain GEMM launch (layer 2)
__global__ __launch_bounds__(256)
void gemm_mfma_k(const float* __restrict__ Xf, const __half* __restrict__ Xh,
                 const __half* __restrict__ Wt, __half* __restrict__ Yh, int nrows,
                 const float* __restrict__ att_s, const float* __restrict__ att_d,
                 float* __restrict__ asb, float* __restrict__ adb) {
    int lane = threadIdx.x & 63;
    int wid  = threadIdx.x >> 6;
    int row0 = (blockIdx.x * 4 + wid) * 16;
    if (row0 < nrows)
        gemm_tile(Xf, Xh, Wt, Yh, nrows, row0, lane, att_s, att_d, asb, adb);
}

// ---- mega kernel: gemm-half (blocks [0,GHALF)) + edge pass (hist or scatter) ----
__global__ __launch_bounds__(256)
void mega_k(const float* __restrict__ Xf, const __half* __restrict__ Wt,
            __half* __restrict__ Yh, int rowBase,
            const float* __restrict__ att_s, const float* __restrict__ att_d,
            float* __restrict__ asb, float* __restrict__ adb,
            int mode,                           // 0 = hist, 1 = scatter
            const int* __restrict__ ei, int* __restrict__ counts,
            int* __restrict__ rank, const int* __restrict__ rp,
            int* __restrict__ csr) {
    int b = blockIdx.x;
    if (b < GHALF) {
        int lane = threadIdx.x & 63;
        int wid  = threadIdx.x >> 6;
        int row0 = rowBase + (b * 4 + wid) * 16;
        if (row0 < NN)
            gemm_tile(Xf, nullptr, Wt, Yh, NN, row0, lane, att_s, att_d, asb, adb);
    } else {
        int i = (b - GHALF) * 256 + threadIdx.x;
        if (i < ET) {
            if (mode == 0) {
                int dst = (i < EE) ? ei[EE + i] : (i - EE);
                rank[i] = atomicAdd(&counts[dst], 1);
            } else {
                int src, dst;
                if (i < EE) { src = ei[i]; dst = ei[EE + i]; }
                else        { src = dst = i - EE; }
                csr[rp[dst] + rank[i]] = src;
            }
        }
    }
}

// ---- prep: transpose W1,W2 (fp32 k-major -> fp16 n-major) + zero counts ----
__global__ void prep_k(const float* __restrict__ W1, __half* __restrict__ Wt1,
                       const float* __restrict__ W2, __half* __restrict__ Wt2,
                       int* __restrict__ counts) {
    int i = blockIdx.x * 256 + threadIdx.x;
    if (i < 16384) {
        int k = i >> 7, n = i & 127;
        Wt1[n * 128 + k] = __float2half(W1[i]);
    } else if (i < 32768) {
        int j = i - 16384;
        int k = j >> 7, n = j & 127;
        Wt2[n * 128 + k] = __float2half(W2[j]);
    } else {
        int j = i - 32768;
        if (j < NN) counts[j] = 0;
    }
}

// ---------------- CSR scans ----------------
__global__ void scan1_k(const int* __restrict__ counts, int* __restrict__ rp,
                        int* __restrict__ bsums) {
    __shared__ int lsum[256];
    int base = blockIdx.x * SCAN_B;
    int v[4];
    int tsum = 0;
#pragma unroll
    for (int j = 0; j < 4; ++j) {
        int i = base + threadIdx.x * 4 + j;
        v[j] = (i < NN) ? counts[i] : 0;
        tsum += v[j];
    }
    lsum[threadIdx.x] = tsum;
    __syncthreads();
    for (int off = 1; off < 256; off <<= 1) {
        int t = (threadIdx.x >= off) ? lsum[threadIdx.x - off] : 0;
        __syncthreads();
        lsum[threadIdx.x] += t;
        __syncthreads();
    }
    int excl = lsum[threadIdx.x] - tsum;
#pragma unroll
    for (int j = 0; j < 4; ++j) {
        int i = base + threadIdx.x * 4 + j;
        if (i < NN) rp[i] = excl;
        excl += v[j];
    }
    if (threadIdx.x == 255) bsums[blockIdx.x] = lsum[255];
}

// merged scan2+scan3: every block redundantly scans the 49 block sums (196 B)
__global__ void scan23_k(int* __restrict__ rp, const int* __restrict__ bsums) {
    __shared__ int sadd;
    int bx = blockIdx.x;
    if (threadIdx.x < 64) {
        int lane = threadIdx.x;
        int v = (lane < NBLK) ? bsums[lane] : 0;
        for (int off = 1; off < 64; off <<= 1) {
            int t = __shfl_up(v, off, 64);
            if (lane >= off) v += t;
        }
        int srcl = (bx == 0) ? 0 : (bx - 1);
        int ex = __shfl(v, srcl, 64);     // inclusive sum at lane bx-1
        if (lane == 0) sadd = (bx == 0) ? 0 : ex;
        if (bx == 0 && lane == 63) rp[NN] = v;   // grand total (== ET)
    }
    __syncthreads();
    int add = sadd;
    int base = bx * SCAN_B + threadIdx.x * 4;
#pragma unroll
    for (int j = 0; j < 4; ++j) {
        int i = base + j;
        if (i < NN) rp[i] += add;
    }
}

// ---- fused softmax + aggregation + bias + ELU (+ optional layer-3 projection) ----
// half-wave (32 lanes) per node, 4 channels per lane
__global__ __launch_bounds__(256)
void agg_k(const __half* __restrict__ Hh, const float* __restrict__ asb,
           const float* __restrict__ adb, const int* __restrict__ rp,
           const int* __restrict__ csr, const float* __restrict__ bias,
           __half* __restrict__ Y,
           const float* __restrict__ W3, const float* __restrict__ s3w,
           const float* __restrict__ d3w, float* __restrict__ h3,
           float* __restrict__ as3, float* __restrict__ ad3) {
    int lane = threadIdx.x & 63;
    int hw = lane >> 5;
    int l  = lane & 31;                   // owns channels l*4 .. l*4+3
    int n = blockIdx.x * 8 + (threadIdx.x >> 6) * 2 + hw;
    if (n >= NN) return;
    int hd = l >> 3;
    float ad = adb[n * 4 + hd];
    float acc0 = 0.f, acc1 = 0.f, acc2 = 0.f, acc3 = 0.f, den = 0.f;
    int e = rp[n], end = rp[n + 1], last = end - 1;
    for (int base = e; base < end; base += 8) {
        int s[8]; float a[8]; float2 hraw[8];
#pragma unroll
        for (int j = 0; j < 8; ++j) {
            int i = base + j;
            s[j] = csr[i <= last ? i : last];
        }
#pragma unroll
        for (int j = 0; j < 8; ++j) a[j] = asb[s[j] * 4 + hd] + ad;
#pragma unroll
        for (int j = 0; j < 8; ++j)
            hraw[j] = ((const float2*)(Hh + (size_t)s[j] * 128))[l];
#pragma unroll
        for (int j = 0; j < 8; ++j) {
            float w = __expf(leaky(a[j]));
            w = (base + j <= last) ? w : 0.f;
            den += w;
            const __half2* hp = (const __half2*)&hraw[j];
            float2 f01 = __half22float2(hp[0]);
            float2 f23 = __half22float2(hp[1]);
            acc0 += w * f01.x; acc1 += w * f01.y;
            acc2 += w * f23.x; acc3 += w * f23.y;
        }
    }
    float4 bv = ((const float4*)bias)[l];
    float inv = 1.f / den;
    float o0 = elu_f(acc0 * inv + bv.x);
    float o1 = elu_f(acc1 * inv + bv.y);
    float o2 = elu_f(acc2 * inv + bv.z);
    float o3 = elu_f(acc3 * inv + bv.w);
    if (!W3) {
        half4 hv;
        hv.a = __floats2half2_rn(o0, o1);
        hv.b = __floats2half2_rn(o2, o3);
        ((half4*)(Y + (size_t)n * 128))[l] = hv;
    } else {
        float4 wa = ((const float4*)W3)[l * 2];
        float4 wb = ((const float4*)W3)[l * 2 + 1];
        float p0 = o0 * wa.x + o1 * wa.z + o2 * wb.x + o3 * wb.z;
        float p1 = o0 * wa.y + o1 * wa.w + o2 * wb.y + o3 * wb.w;
        for (int off = 16; off > 0; off >>= 1) {
            p0 += __shfl_down(p0, off, 32);
            p1 += __shfl_down(p1, off, 32);
        }
        if (l == 0) {
            h3[n * 2 + 0] = p0;
            h3[n * 2 + 1] = p1;
            as3[n] = p0 * s3w[0] + p1 * s3w[1];
            ad3[n] = p0 * d3w[0] + p1 * d3w[1];
        }
    }
}

// ---- layer-3 aggregation + log_softmax ----
__global__ void l3agg_k(const float* __restrict__ h3, const float* __restrict__ as3,
                        const float* __restrict__ ad3, const int* __restrict__ rp,
                        const int* __restrict__ csr, const float* __restrict__ b3,
                        float* __restrict__ out) {
    int n = blockIdx.x * blockDim.x + threadIdx.x;
    if (n >= NN) return;
    const float2* h2 = (const float2*)h3;
    float adn = ad3[n];
    float den = 0.f, a0 = 0.f, a1 = 0.f;
    int e = rp[n], end = rp[n + 1], last = end - 1;
    for (int base = e; base < end; base += 4) {
        int s[4]; float al[4]; float2 g[4];
#pragma unroll
        for (int j = 0; j < 4; ++j) {
            int i = base + j;
            s[j] = csr[i <= last ? i : last];
        }
#pragma unroll
        for (int j = 0; j < 4; ++j) al[j] = as3[s[j]] + adn;
#pragma unroll
        for (int j = 0; j < 4; ++j) g[j] = h2[s[j]];
#pragma unroll
        for (int j = 0; j < 4; ++j) {
            float w = __expf(leaky(al[j]));
            w = (base + j <= last) ? w : 0.f;
            den += w;
            a0 += w * g[j].x;
            a1 += w * g[j].y;
        }
    }
    float o0 = a0 / den + b3[0];
    float o1 = a1 / den + b3[1];
    float m = fmaxf(o0, o1);
    float lse = m + logf(__expf(o0 - m) + __expf(o1 - m));
    out[n * 2 + 0] = o0 - lse;
    out[n * 2 + 1] = o1 - lse;
}

extern "C" void kernel_launch(void* const* d_in, const int* in_sizes, int n_in,
                              void* d_out, int out_size, void* d_ws, size_t ws_size,
                              hipStream_t stream) {
    const float* x   = (const float*)d_in[0];
    const int*   ei  = (const int*)d_in[1];
    const float* W1  = (const float*)d_in[2];
    const float* as1 = (const float*)d_in[3];
    const float* ad1 = (const float*)d_in[4];
    const float* b1  = (const float*)d_in[5];
    const float* W2  = (const float*)d_in[6];
    const float* as2 = (const float*)d_in[7];
    const float* ad2 = (const float*)d_in[8];
    const float* b2  = (const float*)d_in[9];
    const float* W3  = (const float*)d_in[10];
    const float* s3w = (const float*)d_in[11];
    const float* d3w = (const float*)d_in[12];
    const float* b3  = (const float*)d_in[13];
    float* out = (float*)d_out;

    char* ws = (char*)d_ws;
    size_t off = 0;
    auto alloc = [&](size_t bytes) -> char* {
        char* p = ws + off;
        off = (off + bytes + 255) & ~(size_t)255;
        return p;
    };
    __half* hA    = (__half*)alloc((size_t)NN * 128 * 2);   // fp16 gather table
    __half* hBh   = (__half*)alloc((size_t)NN * 128 * 2);   // agg1 out (gemm2 in, fp16)
    float* asb    = (float*)alloc((size_t)NN * 4 * 4);
    float* adb    = (float*)alloc((size_t)NN * 4 * 4);
    int*   rp     = (int*)alloc((size_t)(NN + 1) * 4);
    int*   counts = (int*)alloc((size_t)NN * 4);
    int*   csr    = (int*)alloc((size_t)ET * 4);
    int*   rank   = (int*)alloc((size_t)ET * 4);
    int*   bsums  = (int*)alloc((size_t)NBLK * 4);
    __half* Wt1   = (__half*)alloc(128 * 128 * 2);
    __half* Wt2   = (__half*)alloc(128 * 128 * 2);
    float* h3     = (float*)alloc((size_t)NN * 2 * 4);
    float* s3     = (float*)alloc((size_t)NN * 4);
    float* d3     = (float*)alloc((size_t)NN * 4);

    // 1) weight transposes + zero counts, one launch
    prep_k<<<(32768 + NN + 255) / 256, 256, 0, stream>>>(W1, Wt1, W2, Wt2, counts);

    // 2) megaA: gemm1 rows [0, 25024) || hist (edge histogram + arrival ranks)
    mega_k<<<GHALF + HIST_BLKS, 256, 0, stream>>>(x, Wt1, hA, 0, as1, ad1, asb, adb,
                                                  0, ei, counts, rank, nullptr, nullptr);

    // 3-4) scans (rp = exclusive prefix of counts)
    scan1_k<<<NBLK, 256, 0, stream>>>(counts, rp, bsums);
    scan23_k<<<NBLK, 256, 0, stream>>>(rp, bsums);

    // 5) megaB: gemm1 rows [25024, 50000) || scatter (CSR fill)
    mega_k<<<GHALF + HIST_BLKS, 256, 0, stream>>>(x, Wt1, hA, RHALF, as1, ad1, asb, adb,
                                                  1, ei, counts, rank, rp, csr);

    // 6) Layer-1 softmax/aggregate -> hBh
    agg_k<<<(NN + 7) / 8, 256, 0, stream>>>(hA, asb, adb, rp, csr, b1, hBh,
                                            nullptr, nullptr, nullptr,
                                            nullptr, nullptr, nullptr);

    // 7) Layer 2 GEMM (+ fused alpha)
    gemm_mfma_k<<<(NN + 63) / 64, 256, 0, stream>>>(nullptr, hBh, Wt2, hA, NN,
                                                    as2, ad2, asb, adb);

    // 8) Layer-2 aggregate + fused layer-3 projection/logits
    agg_k<<<(NN + 7) / 8, 256, 0, stream>>>(hA, asb, adb, rp, csr, b2, nullptr,
                                            W3, s3w, d3w, h3, s3, d3);

    // 9) Layer-3 aggregation + log_softmax
    l3agg_k<<<(NN + 255) / 256, 256, 0, stream>>>(h3, s3, d3, rp, csr, b3, out);
}